// Round 15
// baseline (203.194 us; speedup 1.0000x reference)
//
#include <hip/hip_runtime.h>
#include <stdint.h>

typedef __bf16 bf16x8 __attribute__((ext_vector_type(8)));
typedef float f32x4 __attribute__((ext_vector_type(4)));
typedef float f32x16 __attribute__((ext_vector_type(16)));
typedef unsigned u32x2 __attribute__((ext_vector_type(2)));
typedef unsigned u32x4 __attribute__((ext_vector_type(4)));

#define LOG2E 1.44269504088896340736f
#define ATT_SCALE 0.125f
#define CL (ATT_SCALE * LOG2E)
#define SWZ(row, colb) ((colb) ^ (((row) & 7) << 4))

#define GLOAD_LDS16(gp, lp)                                                  \
  __builtin_amdgcn_global_load_lds(                                          \
      (const __attribute__((address_space(1))) void*)(gp),                   \
      (__attribute__((address_space(3))) void*)(lp), 16, 0, 0)

__device__ __forceinline__ unsigned short f2bf(float f) {
  unsigned int x = __float_as_uint(f);
  x += 0x7fffu + ((x >> 16) & 1u);
  return (unsigned short)(x >> 16);
}

__device__ __forceinline__ float fexp2(float x) {
#if __has_builtin(__builtin_amdgcn_exp2f)
  return __builtin_amdgcn_exp2f(x);
#else
  return exp2f(x);
#endif
}

__device__ __forceinline__ unsigned cvtpk(float lo, float hi) {
  unsigned r;
  asm("v_cvt_pk_bf16_f32 %0, %1, %2" : "=v"(r) : "v"(lo), "v"(hi));
  return r;
}

// HW v_permlane32_swap_b32 (pure VALU). Operands MUST be distinct values
// (plswap(x,x) can coalesce into one VGPR and break the exchange — r13 bug).
__device__ __forceinline__ u32x2 plswap(unsigned a, unsigned b) {
  asm("v_permlane32_swap_b32 %0, %1" : "+v"(a), "+v"(b));
  u32x2 r;
  r[0] = a;
  r[1] = b;
  return r;
}

// ------- transpose (x,c -> [B][T][C] bf16) + weight converts, one dispatch ---
__global__ __launch_bounds__(256) void prep_inputs(
    const float* __restrict__ x, const float* __restrict__ c,
    const float* __restrict__ Wq, const float* __restrict__ Wk,
    const float* __restrict__ Wv, const float* __restrict__ Wo,
    unsigned short* __restrict__ xT, unsigned short* __restrict__ cT,
    unsigned short* __restrict__ wqb, unsigned short* __restrict__ wkb,
    unsigned short* __restrict__ wvb, unsigned short* __restrict__ wob) {
  const int C = 1024, T = 2048;
  int z = blockIdx.z;
  if (z >= 8) {
    int sel = z - 8;
    int bi = blockIdx.y * 64 + blockIdx.x;               // 0..2047
    if (bi >= 512) return;                               // 512 x 256 x 8 = 1M elems
    const float* in = sel == 0 ? Wq : sel == 1 ? Wk : sel == 2 ? Wv : Wo;
    unsigned short* out = sel == 0 ? wqb : sel == 1 ? wkb : sel == 2 ? wvb : wob;
    float scale = sel == 0 ? CL : 1.0f;
    int off = (bi * 256 + threadIdx.x) * 8;
    #pragma unroll
    for (int p = 0; p < 2; ++p) {
      float4 v = *(const float4*)(in + off + p * 4);
      ushort4 o;
      o.x = f2bf(v.x * scale); o.y = f2bf(v.y * scale);
      o.z = f2bf(v.z * scale); o.w = f2bf(v.w * scale);
      *(ushort4*)(out + off + p * 4) = o;
    }
    return;
  }
  __shared__ unsigned short tile[32][33];
  const float* in = (z < 4) ? x : c;
  unsigned short* out = (z < 4) ? xT : cT;
  int b = z & 3;
  int t0 = blockIdx.x * 32, c0 = blockIdx.y * 32;
  int tx = threadIdx.x & 31, ty = threadIdx.x >> 5;
  const float* src = in + ((size_t)b * C + c0) * T + t0;
  #pragma unroll
  for (int i = 0; i < 4; ++i) {
    int cc = ty + i * 8;
    tile[cc][tx] = f2bf(src[(size_t)cc * T + tx]);
  }
  __syncthreads();
  unsigned short* dst = out + ((size_t)b * T + t0) * C + c0;
  #pragma unroll
  for (int i = 0; i < 4; ++i) {
    int tt = ty + i * 8;
    dst[(size_t)tt * C + tx] = tile[tx][tt];
  }
}

// ============ 128x128 NT GEMM core, BK=32, TRIPLE-buffered, counted vmcnt ====
template <int NT, int OUT_F32>
__device__ __forceinline__ void gemm_core128(
    const unsigned short* __restrict__ A, const unsigned short* __restrict__ B,
    void* __restrict__ Cv, const float* __restrict__ bias, int bias_is_m,
    float bs, int m0, int n0, int ldC) {
  __shared__ __align__(16) char lds[3 * 16384];
  const int tid = threadIdx.x;
  const int l = tid & 63, w = tid >> 6;
  const int g = l >> 4, j = l & 15;
  const int wr = w >> 1, wc = w & 1;

  const int r0 = tid >> 3;
  const int slotp = (tid & 7) ^ (r0 & 7);
  const int mloc = r0 * 2 + (slotp >> 2);
  const int kg = slotp & 3;
  const unsigned short* ga0 = A + (size_t)(m0 + mloc) * 1024 + kg * 8;
  const unsigned short* ga1 = A + (size_t)(m0 + 64 + mloc) * 1024 + kg * 8;
  const unsigned short* gb0 = B + (size_t)(n0 + mloc) * 1024 + kg * 8;
  const unsigned short* gb1 = B + (size_t)(n0 + 64 + mloc) * 1024 + kg * 8;

  auto stage = [&](char* buf) {
    GLOAD_LDS16(ga0, buf + tid * 16);
    GLOAD_LDS16(ga1, buf + 4096 + tid * 16);
    GLOAD_LDS16(gb0, buf + 8192 + tid * 16);
    GLOAD_LDS16(gb1, buf + 12288 + tid * 16);
    ga0 += 32; ga1 += 32; gb0 += 32; gb1 += 32;
  };

  f32x4 acc[4][4] = {};

  stage(lds);
  stage(lds + 16384);

  char* bufc = lds;
  char* bufs = lds + 2 * 16384;

  for (int t = 0; t < NT; ++t) {
    if (t == NT - 1) asm volatile("s_waitcnt vmcnt(0)" ::: "memory");
    else             asm volatile("s_waitcnt vmcnt(4)" ::: "memory");
    __builtin_amdgcn_s_barrier();
    asm volatile("" ::: "memory");
    if (t < NT - 2) stage(bufs);

    bf16x8 af[4], bfr[4];
    #pragma unroll
    for (int mf = 0; mf < 4; ++mf) {
      int m = wr * 64 + mf * 16 + j;
      int rp = m >> 1;
      int cb = ((m & 1) * 64 + g * 16) ^ ((rp & 7) << 4);
      af[mf] = *(const bf16x8*)(bufc + rp * 128 + cb);
    }
    #pragma unroll
    for (int nf = 0; nf < 4; ++nf) {
      int n = wc * 64 + nf * 16 + j;
      int rp = n >> 1;
      int cb = ((n & 1) * 64 + g * 16) ^ ((rp & 7) << 4);
      bfr[nf] = *(const bf16x8*)(bufc + 8192 + rp * 128 + cb);
    }
    #pragma unroll
    for (int mf = 0; mf < 4; ++mf)
      #pragma unroll
      for (int nf = 0; nf < 4; ++nf)
        acc[mf][nf] = __builtin_amdgcn_mfma_f32_16x16x32_bf16(af[mf], bfr[nf], acc[mf][nf], 0, 0, 0);

    bufc += 16384; if (bufc == lds + 49152) bufc = lds;
    bufs += 16384; if (bufs == lds + 49152) bufs = lds;
  }

  #pragma unroll
  for (int mf = 0; mf < 4; ++mf) {
    #pragma unroll
    for (int rr = 0; rr < 4; ++rr) {
      int m = m0 + wr * 64 + mf * 16 + g * 4 + rr;
      float bm = bias_is_m ? bias[m] * bs : 0.f;
      #pragma unroll
      for (int nf = 0; nf < 4; ++nf) {
        int n = n0 + wc * 64 + nf * 16 + j;
        float val = acc[mf][nf][rr] + bm + (bias_is_m ? 0.f : bias[n] * bs);
        if (OUT_F32) ((float*)Cv)[(size_t)m * ldC + n] = val;
        else ((unsigned short*)Cv)[(size_t)m * ldC + n] = f2bf(val);
      }
    }
  }
}

// ======= Q/K projections: B (weights) DIRECT from global into fragments =====
// A-only tri-buffered LDS (3 x 8KB). Per body t: load B(t+1) regs (4x16B/lane,
// L1/L2-hot), stage A(t+2) (2 gload_lds). Waits: vmcnt(6) steady, vmcnt(4)
// final — FIFO-safe even under load reordering (consumed B provably complete).
// grid 1024 XCD-chunked, 256 thr.
__global__ __launch_bounds__(256, 2) void qkv_qk(
    const unsigned short* __restrict__ xT, const unsigned short* __restrict__ cT,
    const unsigned short* __restrict__ wq, const unsigned short* __restrict__ wk,
    const float* __restrict__ bq, const float* __restrict__ bk,
    unsigned short* __restrict__ QT, unsigned short* __restrict__ KT) {
  __shared__ __align__(16) char lds[3 * 8192];
  const size_t sBT = (size_t)2048 * 1024;

  const int id = (blockIdx.x & 7) * 128 + (blockIdx.x >> 3);  // XCD chunking
  const int op = id >> 9;
  const int r = id & 511;
  const int z = r >> 7;
  const int m0 = ((r >> 3) & 15) * 128, n0 = (r & 7) * 128;
  const unsigned short* A = (op == 0 ? xT : cT) + z * sBT;
  const unsigned short* Bw = (op == 0 ? wq : wk);
  unsigned short* Cp = (op == 0 ? QT : KT) + z * sBT;
  const float* bias = (op == 0 ? bq : bk);
  const float bs = (op == 0) ? CL : 1.0f;

  const int tid = threadIdx.x;
  const int l = tid & 63, w = tid >> 6;
  const int g = l >> 4, j = l & 15;
  const int wr = w >> 1, wc = w & 1;

  // A staging coords (identical math to green core, A half only)
  const int r0 = tid >> 3;
  const int slotp = (tid & 7) ^ (r0 & 7);
  const int mloc = r0 * 2 + (slotp >> 2);
  const int kg = slotp & 3;
  const unsigned short* ga0 = A + (size_t)(m0 + mloc) * 1024 + kg * 8;
  const unsigned short* ga1 = A + (size_t)(m0 + 64 + mloc) * 1024 + kg * 8;

  // per-lane B base: row n0 + wc*64 + j, k-bytes g*16 (lane reads 16B)
  const unsigned short* pb = Bw + (size_t)(n0 + wc * 64 + j) * 1024 + g * 8;

  f32x4 acc[4][4] = {};
  bf16x8 bfrA[4], bfrB[4];

  // prologue: A(0)->buf0, A(1)->buf1 (4 gloads), B(0)->bfrA (4 loads)
  GLOAD_LDS16(ga0, lds + tid * 16);
  GLOAD_LDS16(ga1, lds + 4096 + tid * 16);
  ga0 += 32; ga1 += 32;
  GLOAD_LDS16(ga0, lds + 8192 + tid * 16);
  GLOAD_LDS16(ga1, lds + 12288 + tid * 16);
  ga0 += 32; ga1 += 32;
  bfrA[0] = *(const bf16x8*)(pb);
  bfrA[1] = *(const bf16x8*)(pb + 16 * 1024);
  bfrA[2] = *(const bf16x8*)(pb + 32 * 1024);
  bfrA[3] = *(const bf16x8*)(pb + 48 * 1024);
  pb += 32;

  char* bufc = lds;
  char* bufs = lds + 2 * 8192;

#define QK_BODY(USEB, LOADB, DO_LOADB, DO_STAGE, WAITN)                      \
  do {                                                                       \
    asm volatile("s_waitcnt vmcnt(" #WAITN ")" ::: "memory");                \
    __builtin_amdgcn_s_barrier();                                            \
    asm volatile("" ::: "memory");                                           \
    if (DO_LOADB) {                                                          \
      LOADB[0] = *(const bf16x8*)(pb);                                       \
      LOADB[1] = *(const bf16x8*)(pb + 16 * 1024);                           \
      LOADB[2] = *(const bf16x8*)(pb + 32 * 1024);                           \
      LOADB[3] = *(const bf16x8*)(pb + 48 * 1024);                           \
      pb += 32;                                                              \
    }                                                                        \
    if (DO_STAGE) {                                                          \
      GLOAD_LDS16(ga0, bufs + tid * 16);                                     \
      GLOAD_LDS16(ga1, bufs + 4096 + tid * 16);                              \
      ga0 += 32; ga1 += 32;                                                  \
    }                                                                        \
    bf16x8 af[4];                                                            \
    _Pragma("unroll")                                                        \
    for (int mf = 0; mf < 4; ++mf) {                                         \
      int m = wr * 64 + mf * 16 + j;                                         \
      int rp = m >> 1;                                                       \
      int cb = ((m & 1) * 64 + g * 16) ^ ((rp & 7) << 4);                    \
      af[mf] = *(const bf16x8*)(bufc + rp * 128 + cb);                       \
    }                                                                        \
    _Pragma("unroll")                                                        \
    for (int mf = 0; mf < 4; ++mf)                                           \
      _Pragma("unroll")                                                      \
      for (int nf = 0; nf < 4; ++nf)                                         \
        acc[mf][nf] = __builtin_amdgcn_mfma_f32_16x16x32_bf16(               \
            af[mf], USEB[nf], acc[mf][nf], 0, 0, 0);                         \
    bufc += 8192; if (bufc == lds + 24576) bufc = lds;                       \
    bufs += 8192; if (bufs == lds + 24576) bufs = lds;                       \
  } while (0)

  // bodies 0..29 (15 pairs), all steady-state
  for (int t = 0; t < 30; t += 2) {
    QK_BODY(bfrA, bfrB, 1, 1, 6);   // even body: use B(t),  load B(t+1), stage A(t+2)
    QK_BODY(bfrB, bfrA, 1, 1, 6);   // odd body:  use B(t+1),load B(t+2), stage A(t+3)
  }
  QK_BODY(bfrA, bfrB, 1, 0, 6);     // body 30: use B(30), load B(31), no stage
  QK_BODY(bfrB, bfrA, 0, 0, 4);     // body 31: use B(31)
#undef QK_BODY

  #pragma unroll
  for (int mf = 0; mf < 4; ++mf) {
    #pragma unroll
    for (int rr = 0; rr < 4; ++rr) {
      int m = m0 + wr * 64 + mf * 16 + g * 4 + rr;
      #pragma unroll
      for (int nf = 0; nf < 4; ++nf) {
        int n = n0 + wc * 64 + nf * 16 + j;
        Cp[(size_t)m * 1024 + n] = f2bf(acc[mf][nf][rr] + bias[n] * bs);
      }
    }
  }
}

// ---------------- V projection: green core, grid 512 (XCD-chunked) ----------
__global__ __launch_bounds__(256, 3) void qkv_v(
    const unsigned short* __restrict__ cT, const unsigned short* __restrict__ wv,
    const float* __restrict__ bv, unsigned short* __restrict__ Vb) {
  const size_t sBT = (size_t)2048 * 1024;
  const int id = (blockIdx.x & 7) * 64 + (blockIdx.x >> 3);
  const int z = id >> 7;
  const int r = id & 127;
  const int n0 = (r & 15) * 128, m0 = ((r >> 4) & 7) * 128;
  gemm_core128<32, 0>(wv, cT + z * sBT, Vb + z * (size_t)1024 * 2048,
                      bv, 1, 1.0f, m0, n0, 2048);
}

// ---------------- output projection: grid 512 (XCD-chunked), fp32 out --------
__global__ __launch_bounds__(256, 3) void gemm_out3(
    const unsigned short* __restrict__ Wo, const unsigned short* __restrict__ OT,
    float* __restrict__ Out, const float* __restrict__ bias) {
  const size_t sBT = (size_t)2048 * 1024;
  const int id = (blockIdx.x & 7) * 64 + (blockIdx.x >> 3);
  const int z = id >> 7;
  const int m0 = ((id >> 4) & 7) * 128, n0 = (id & 15) * 128;
  gemm_core128<32, 1>(Wo, OT + z * sBT, Out + z * (size_t)1024 * 2048,
                      bias, 1, 1.0f, m0, n0, 2048);
}

// ---- flash attention v8b: tri-buffered K/V + 64 q-rows/wave (tb=2) ---------
__global__ __launch_bounds__(256, 2) void attn_kernel8(const unsigned short* __restrict__ QT,
                                                       const unsigned short* __restrict__ KT,
                                                       const unsigned short* __restrict__ V,
                                                       unsigned short* __restrict__ OT) {
  __shared__ __align__(16) char kv[3][16384];   // [buf][Ks 8K | Vs 8K]
  __shared__ float lbuf[4][32];

  const int fid = blockIdx.x;              // 0..511
  const int xcd = fid & 7, idx = fid >> 3; // idx 0..63
  const int bh = ((idx & 7) << 3) | xcd;   // 8 bh per XCD
  const int tblk = idx >> 3;               // 0..7
  const int b = bh >> 4, h = bh & 15;

  const int tid = threadIdx.x;
  const int w = tid >> 6, l = tid & 63, lo5 = l & 31, hi = l >> 5;
  const int tq0 = tblk * 256 + w * 64;

  bf16x8 q[2][4];
  {
    const unsigned short* Qb = QT + ((size_t)(b * 2048 + tq0 + lo5)) * 1024 + h * 64 + hi * 8;
    #pragma unroll
    for (int tb = 0; tb < 2; ++tb)
      #pragma unroll
      for (int kb = 0; kb < 4; ++kb)
        q[tb][kb] = *(const bf16x8*)(Qb + (size_t)tb * 32 * 1024 + kb * 16);
  }

  f32x16 o[2][2] = {};
  float lr[2] = {0.f, 0.f};

  const int srow0 = tid >> 3, sslot = tid & 7;
  const int ch0 = sslot ^ (srow0 & 7);
  const int ch1 = sslot ^ ((32 + srow0) & 7);
  const unsigned short* kp0 = KT + ((size_t)(b * 2048 + srow0)) * 1024 + h * 64 + ch0 * 8;
  const unsigned short* kp1 = KT + ((size_t)(b * 2048 + 32 + srow0)) * 1024 + h * 64 + ch1 * 8;
  const unsigned short* vp0 = V + ((size_t)(b * 1024 + h * 64 + srow0)) * 2048 + ch0 * 8;
  const unsigned short* vp1 = V + ((size_t)(b * 1024 + h * 64 + 32 + srow0)) * 2048 + ch1 * 8;

  auto stage = [&](char* buf) {
    GLOAD_LDS16(kp0, buf + tid * 16);
    GLOAD_LDS16(kp1, buf + 4096 + tid * 16);
    GLOAD_LDS16(vp0, buf + 8192 + tid * 16);
    GLOAD_LDS16(vp1, buf + 12288 + tid * 16);
    kp0 += 64 * 1024; kp1 += 64 * 1024;
    vp0 += 64; vp1 += 64;
  };

  stage(kv[0]);
  stage(kv[1]);

  char* bufc = kv[0];
  char* bufs = kv[2];

  for (int t = 0; t < 32; ++t) {
    if (t == 31) asm volatile("s_waitcnt vmcnt(0)" ::: "memory");
    else         asm volatile("s_waitcnt vmcnt(4)" ::: "memory");
    __builtin_amdgcn_s_barrier();
    asm volatile("" ::: "memory");
    if (t < 30) stage(bufs);

    const char* Ks = bufc;
    const char* Vs = bufc + 8192;

    bf16x8 ka[2][4];
    #pragma unroll
    for (int sblk = 0; sblk < 2; ++sblk)
      #pragma unroll
      for (int kb = 0; kb < 4; ++kb) {
        int row = sblk * 32 + lo5;
        ka[sblk][kb] = *(const bf16x8*)(Ks + row * 128 + SWZ(row, kb * 32 + hi * 16));
      }

    u32x4 pa[2][4];
    #pragma unroll
    for (int tb = 0; tb < 2; ++tb) {
      f32x16 p0 = {}, p1 = {};
      #pragma unroll
      for (int kb = 0; kb < 4; ++kb) {
        p0 = __builtin_amdgcn_mfma_f32_32x32x16_bf16(ka[0][kb], q[tb][kb], p0, 0, 0, 0);
        p1 = __builtin_amdgcn_mfma_f32_32x32x16_bf16(ka[1][kb], q[tb][kb], p1, 0, 0, 0);
      }

      float ls0 = 0.f, ls1 = 0.f, ls2 = 0.f, ls3 = 0.f;
      #pragma unroll
      for (int r = 0; r < 16; r += 4) {
        float e0 = fexp2(p0[r]), e1 = fexp2(p0[r + 1]), e2 = fexp2(p0[r + 2]), e3 = fexp2(p0[r + 3]);
        p0[r] = e0; p0[r + 1] = e1; p0[r + 2] = e2; p0[r + 3] = e3;
        ls0 += e0; ls1 += e1; ls2 += e2; ls3 += e3;
      }
      #pragma unroll
      for (int r = 0; r < 16; r += 4) {
        float e0 = fexp2(p1[r]), e1 = fexp2(p1[r + 1]), e2 = fexp2(p1[r + 2]), e3 = fexp2(p1[r + 3]);
        p1[r] = e0; p1[r + 1] = e1; p1[r + 2] = e2; p1[r + 3] = e3;
        ls0 += e0; ls1 += e1; ls2 += e2; ls3 += e3;
      }
      lr[tb] += (ls0 + ls1) + (ls2 + ls3);

      u32x2 ra = plswap(cvtpk(p0[0], p0[1]), cvtpk(p0[4], p0[5]));
      u32x2 rb = plswap(cvtpk(p0[2], p0[3]), cvtpk(p0[6], p0[7]));
      pa[tb][0] = (u32x4){ra[0], rb[0], ra[1], rb[1]};
      u32x2 rc = plswap(cvtpk(p0[8], p0[9]), cvtpk(p0[12], p0[13]));
      u32x2 rd = plswap(cvtpk(p0[10], p0[11]), cvtpk(p0[14], p0[15]));
      pa[tb][1] = (u32x4){rc[0], rd[0], rc[1], rd[1]};
      u32x2 re = plswap(cvtpk(p1[0], p1[1]), cvtpk(p1[4], p1[5]));
      u32x2 rf = plswap(cvtpk(p1[2], p1[3]), cvtpk(p1[6], p1[7]));
      pa[tb][2] = (u32x4){re[0], rf[0], re[1], rf[1]};
      u32x2 rg = plswap(cvtpk(p1[8], p1[9]), cvtpk(p1[12], p1[13]));
      u32x2 rh = plswap(cvtpk(p1[10], p1[11]), cvtpk(p1[14], p1[15]));
      pa[tb][3] = (u32x4){rg[0], rh[0], rg[1], rh[1]};
    }

    #pragma unroll
    for (int sb = 0; sb < 4; ++sb)
      #pragma unroll
      for (int kb2 = 0; kb2 < 2; ++kb2) {
        int row = kb2 * 32 + lo5;
        bf16x8 vb = *(const bf16x8*)(Vs + row * 128 + SWZ(row, sb * 32 + hi * 16));
        o[0][kb2] = __builtin_amdgcn_mfma_f32_32x32x16_bf16(
            __builtin_bit_cast(bf16x8, pa[0][sb]), vb, o[0][kb2], 0, 0, 0);
        o[1][kb2] = __builtin_amdgcn_mfma_f32_32x32x16_bf16(
            __builtin_bit_cast(bf16x8, pa[1][sb]), vb, o[1][kb2], 0, 0, 0);
      }

    bufc += 16384; if (bufc == kv[0] + 49152) bufc = kv[0];
    bufs += 16384; if (bufs == kv[0] + 49152) bufs = kv[0];
  }

  #pragma unroll
  for (int tb = 0; tb < 2; ++tb) {
    float lt = lr[tb] + __shfl_xor(lr[tb], 32);
    if (hi == 0) lbuf[w][lo5] = 1.0f / lt;
    unsigned short* Ob = OT + ((size_t)(b * 2048 + tq0 + tb * 32)) * 1024 + h * 64 + lo5;
    #pragma unroll
    for (int r = 0; r < 16; ++r) {
      int srow = (r & 3) + 8 * (r >> 2) + 4 * hi;
      float inv = lbuf[w][srow];
      Ob[(size_t)srow * 1024 + 0]  = f2bf(o[tb][0][r] * inv);
      Ob[(size_t)srow * 1024 + 32] = f2bf(o[tb][1][r] * inv);
    }
  }
}

// ---------------- launch ----------------
extern "C" void kernel_launch(void* const* d_in, const int* in_sizes, int n_in,
                              void* d_out, int out_size, void* d_ws, size_t ws_size,
                              hipStream_t stream) {
  const float* x  = (const float*)d_in[0];
  const float* c  = (const float*)d_in[1];
  const float* Wq = (const float*)d_in[2];
  const float* bq = (const float*)d_in[3];
  const float* Wk = (const float*)d_in[4];
  const float* bk = (const float*)d_in[5];
  const float* Wv = (const float*)d_in[6];
  const float* bv = (const float*)d_in[7];
  const float* Wo = (const float*)d_in[8];
  const float* bo = (const float*)d_in[9];

  const size_t MB = 1024 * 1024;
  char* ws = (char*)d_ws;
  unsigned short* wqb = (unsigned short*)(ws + 0 * MB);
  unsigned short* wkb = (unsigned short*)(ws + 2 * MB);
  unsigned short* wvb = (unsigned short*)(ws + 4 * MB);
  unsigned short* wob = (unsigned short*)(ws + 6 * MB);
  unsigned short* xT  = (unsigned short*)(ws + 8 * MB);   // [B][T][C] bf16, 16MB
  unsigned short* cT  = (unsigned short*)(ws + 24 * MB);
  unsigned short* QT  = (unsigned short*)(ws + 40 * MB);
  unsigned short* KT  = (unsigned short*)(ws + 56 * MB);
  unsigned short* Vb  = (unsigned short*)(ws + 72 * MB);  // [B][C][T] bf16
  unsigned short* OT  = xT;  // reuse: x dead after Q projection

  prep_inputs<<<dim3(64, 32, 12), 256, 0, stream>>>(x, c, Wq, Wk, Wv, Wo,
                                                    xT, cT, wqb, wkb, wvb, wob);

  qkv_qk<<<dim3(1024), 256, 0, stream>>>(xT, cT, wqb, wkb, bq, bk, QT, KT);
  qkv_v<<<dim3(512), 256, 0, stream>>>(cT, wvb, bv, Vb);

  attn_kernel8<<<dim3(512), 256, 0, stream>>>(QT, KT, Vb, OT);

  gemm_out3<<<dim3(512), 256, 0, stream>>>(wob, OT, (float*)d_out, bo);
}

// Round 16
// 181.521 us; speedup vs baseline: 1.1194x; 1.1194x over previous
//
#include <hip/hip_runtime.h>
#include <stdint.h>

typedef __bf16 bf16x8 __attribute__((ext_vector_type(8)));
typedef float f32x4 __attribute__((ext_vector_type(4)));
typedef float f32x16 __attribute__((ext_vector_type(16)));
typedef unsigned u32x2 __attribute__((ext_vector_type(2)));
typedef unsigned u32x4 __attribute__((ext_vector_type(4)));

#define LOG2E 1.44269504088896340736f
#define ATT_SCALE 0.125f
#define CL (ATT_SCALE * LOG2E)
#define SWZ(row, colb) ((colb) ^ (((row) & 7) << 4))

#define GLOAD_LDS16(gp, lp)                                                  \
  __builtin_amdgcn_global_load_lds(                                          \
      (const __attribute__((address_space(1))) void*)(gp),                   \
      (__attribute__((address_space(3))) void*)(lp), 16, 0, 0)

__device__ __forceinline__ unsigned short f2bf(float f) {
  unsigned int x = __float_as_uint(f);
  x += 0x7fffu + ((x >> 16) & 1u);
  return (unsigned short)(x >> 16);
}

__device__ __forceinline__ float fexp2(float x) {
#if __has_builtin(__builtin_amdgcn_exp2f)
  return __builtin_amdgcn_exp2f(x);
#else
  return exp2f(x);
#endif
}

__device__ __forceinline__ unsigned cvtpk(float lo, float hi) {
  unsigned r;
  asm("v_cvt_pk_bf16_f32 %0, %1, %2" : "=v"(r) : "v"(lo), "v"(hi));
  return r;
}

// HW v_permlane32_swap_b32 (pure VALU). Operands MUST be distinct values
// (plswap(x,x) can coalesce into one VGPR and break the exchange — r13 bug).
__device__ __forceinline__ u32x2 plswap(unsigned a, unsigned b) {
  asm("v_permlane32_swap_b32 %0, %1" : "+v"(a), "+v"(b));
  u32x2 r;
  r[0] = a;
  r[1] = b;
  return r;
}

// ------- transpose (x,c -> [B][T][C] bf16) + weight converts, one dispatch ---
__global__ __launch_bounds__(256) void prep_inputs(
    const float* __restrict__ x, const float* __restrict__ c,
    const float* __restrict__ Wq, const float* __restrict__ Wk,
    const float* __restrict__ Wv, const float* __restrict__ Wo,
    unsigned short* __restrict__ xT, unsigned short* __restrict__ cT,
    unsigned short* __restrict__ wqb, unsigned short* __restrict__ wkb,
    unsigned short* __restrict__ wvb, unsigned short* __restrict__ wob) {
  const int C = 1024, T = 2048;
  int z = blockIdx.z;
  if (z >= 8) {
    int sel = z - 8;
    int bi = blockIdx.y * 64 + blockIdx.x;               // 0..2047
    if (bi >= 512) return;                               // 512 x 256 x 8 = 1M elems
    const float* in = sel == 0 ? Wq : sel == 1 ? Wk : sel == 2 ? Wv : Wo;
    unsigned short* out = sel == 0 ? wqb : sel == 1 ? wkb : sel == 2 ? wvb : wob;
    float scale = sel == 0 ? CL : 1.0f;
    int off = (bi * 256 + threadIdx.x) * 8;
    #pragma unroll
    for (int p = 0; p < 2; ++p) {
      float4 v = *(const float4*)(in + off + p * 4);
      ushort4 o;
      o.x = f2bf(v.x * scale); o.y = f2bf(v.y * scale);
      o.z = f2bf(v.z * scale); o.w = f2bf(v.w * scale);
      *(ushort4*)(out + off + p * 4) = o;
    }
    return;
  }
  __shared__ unsigned short tile[32][33];
  const float* in = (z < 4) ? x : c;
  unsigned short* out = (z < 4) ? xT : cT;
  int b = z & 3;
  int t0 = blockIdx.x * 32, c0 = blockIdx.y * 32;
  int tx = threadIdx.x & 31, ty = threadIdx.x >> 5;
  const float* src = in + ((size_t)b * C + c0) * T + t0;
  #pragma unroll
  for (int i = 0; i < 4; ++i) {
    int cc = ty + i * 8;
    tile[cc][tx] = f2bf(src[(size_t)cc * T + tx]);
  }
  __syncthreads();
  unsigned short* dst = out + ((size_t)b * T + t0) * C + c0;
  #pragma unroll
  for (int i = 0; i < 4; ++i) {
    int tt = ty + i * 8;
    dst[(size_t)tt * C + tx] = tile[tx][tt];
  }
}

// ============ 128x128 NT GEMM core, BK=32, TRIPLE-buffered, counted vmcnt ====
template <int NT, int OUT_F32>
__device__ __forceinline__ void gemm_core128(
    const unsigned short* __restrict__ A, const unsigned short* __restrict__ B,
    void* __restrict__ Cv, const float* __restrict__ bias, int bias_is_m,
    float bs, int m0, int n0, int ldC) {
  __shared__ __align__(16) char lds[3 * 16384];
  const int tid = threadIdx.x;
  const int l = tid & 63, w = tid >> 6;
  const int g = l >> 4, j = l & 15;
  const int wr = w >> 1, wc = w & 1;

  const int r0 = tid >> 3;
  const int slotp = (tid & 7) ^ (r0 & 7);
  const int mloc = r0 * 2 + (slotp >> 2);
  const int kg = slotp & 3;
  const unsigned short* ga0 = A + (size_t)(m0 + mloc) * 1024 + kg * 8;
  const unsigned short* ga1 = A + (size_t)(m0 + 64 + mloc) * 1024 + kg * 8;
  const unsigned short* gb0 = B + (size_t)(n0 + mloc) * 1024 + kg * 8;
  const unsigned short* gb1 = B + (size_t)(n0 + 64 + mloc) * 1024 + kg * 8;

  auto stage = [&](char* buf) {
    GLOAD_LDS16(ga0, buf + tid * 16);
    GLOAD_LDS16(ga1, buf + 4096 + tid * 16);
    GLOAD_LDS16(gb0, buf + 8192 + tid * 16);
    GLOAD_LDS16(gb1, buf + 12288 + tid * 16);
    ga0 += 32; ga1 += 32; gb0 += 32; gb1 += 32;
  };

  f32x4 acc[4][4] = {};

  stage(lds);
  stage(lds + 16384);

  char* bufc = lds;
  char* bufs = lds + 2 * 16384;

  for (int t = 0; t < NT; ++t) {
    if (t == NT - 1) asm volatile("s_waitcnt vmcnt(0)" ::: "memory");
    else             asm volatile("s_waitcnt vmcnt(4)" ::: "memory");
    __builtin_amdgcn_s_barrier();
    asm volatile("" ::: "memory");
    if (t < NT - 2) stage(bufs);

    bf16x8 af[4], bfr[4];
    #pragma unroll
    for (int mf = 0; mf < 4; ++mf) {
      int m = wr * 64 + mf * 16 + j;
      int rp = m >> 1;
      int cb = ((m & 1) * 64 + g * 16) ^ ((rp & 7) << 4);
      af[mf] = *(const bf16x8*)(bufc + rp * 128 + cb);
    }
    #pragma unroll
    for (int nf = 0; nf < 4; ++nf) {
      int n = wc * 64 + nf * 16 + j;
      int rp = n >> 1;
      int cb = ((n & 1) * 64 + g * 16) ^ ((rp & 7) << 4);
      bfr[nf] = *(const bf16x8*)(bufc + 8192 + rp * 128 + cb);
    }
    #pragma unroll
    for (int mf = 0; mf < 4; ++mf)
      #pragma unroll
      for (int nf = 0; nf < 4; ++nf)
        acc[mf][nf] = __builtin_amdgcn_mfma_f32_16x16x32_bf16(af[mf], bfr[nf], acc[mf][nf], 0, 0, 0);

    bufc += 16384; if (bufc == lds + 49152) bufc = lds;
    bufs += 16384; if (bufs == lds + 49152) bufs = lds;
  }

  #pragma unroll
  for (int mf = 0; mf < 4; ++mf) {
    #pragma unroll
    for (int rr = 0; rr < 4; ++rr) {
      int m = m0 + wr * 64 + mf * 16 + g * 4 + rr;
      float bm = bias_is_m ? bias[m] * bs : 0.f;
      #pragma unroll
      for (int nf = 0; nf < 4; ++nf) {
        int n = n0 + wc * 64 + nf * 16 + j;
        float val = acc[mf][nf][rr] + bm + (bias_is_m ? 0.f : bias[n] * bs);
        if (OUT_F32) ((float*)Cv)[(size_t)m * ldC + n] = val;
        else ((unsigned short*)Cv)[(size_t)m * ldC + n] = f2bf(val);
      }
    }
  }
}

// ---------------- fused QKV GEMM: grid 1536 (XCD-chunked), 256 thr -----------
__global__ __launch_bounds__(256, 3) void qkv_gemm3(
    const unsigned short* __restrict__ xT, const unsigned short* __restrict__ cT,
    const unsigned short* __restrict__ wq, const unsigned short* __restrict__ wk,
    const unsigned short* __restrict__ wv,
    const float* __restrict__ bq, const float* __restrict__ bk,
    const float* __restrict__ bv,
    unsigned short* __restrict__ QT, unsigned short* __restrict__ KT,
    unsigned short* __restrict__ Vb) {
  const size_t sBT = (size_t)2048 * 1024;
  const int id = (blockIdx.x & 7) * 192 + (blockIdx.x >> 3);  // XCD chunking
  const int op = id >> 9;
  const int r = id & 511;
  const int z = r >> 7;
  const unsigned short *A, *B;
  unsigned short* Cp;
  const float* bias;
  int m0, n0, ldC, bias_is_m;
  float bs;
  if (op == 2) {
    n0 = (r & 15) * 128; m0 = ((r >> 4) & 7) * 128;
    A = wv; B = cT + z * sBT; Cp = Vb + z * (size_t)1024 * 2048;
    bias = bv; ldC = 2048; bias_is_m = 1; bs = 1.0f;
  } else {
    n0 = (r & 7) * 128; m0 = ((r >> 3) & 15) * 128;
    A = (op == 0 ? xT : cT) + z * sBT;
    B = (op == 0 ? wq : wk);
    Cp = (op == 0 ? QT : KT) + z * sBT;
    bias = (op == 0 ? bq : bk); ldC = 1024; bias_is_m = 0;
    bs = (op == 0) ? CL : 1.0f;
  }
  gemm_core128<32, 0>(A, B, Cp, bias, bias_is_m, bs, m0, n0, ldC);
}

// ---------------- output projection: grid 512 (XCD-chunked), fp32 out --------
__global__ __launch_bounds__(256, 3) void gemm_out3(
    const unsigned short* __restrict__ Wo, const unsigned short* __restrict__ OT,
    float* __restrict__ Out, const float* __restrict__ bias) {
  const size_t sBT = (size_t)2048 * 1024;
  const int id = (blockIdx.x & 7) * 64 + (blockIdx.x >> 3);
  const int z = id >> 7;
  const int m0 = ((id >> 4) & 7) * 128, n0 = (id & 15) * 128;
  gemm_core128<32, 1>(Wo, OT + z * sBT, Out + z * (size_t)1024 * 2048,
                      bias, 1, 1.0f, m0, n0, 2048);
}

// ---- flash attention v8b: tri-buffered K/V + 64 q-rows/wave (tb=2) ---------
__global__ __launch_bounds__(256, 2) void attn_kernel8(const unsigned short* __restrict__ QT,
                                                       const unsigned short* __restrict__ KT,
                                                       const unsigned short* __restrict__ V,
                                                       unsigned short* __restrict__ OT) {
  __shared__ __align__(16) char kv[3][16384];   // [buf][Ks 8K | Vs 8K]
  __shared__ float lbuf[4][32];

  const int fid = blockIdx.x;              // 0..511
  const int xcd = fid & 7, idx = fid >> 3; // idx 0..63
  const int bh = ((idx & 7) << 3) | xcd;   // 8 bh per XCD
  const int tblk = idx >> 3;               // 0..7
  const int b = bh >> 4, h = bh & 15;

  const int tid = threadIdx.x;
  const int w = tid >> 6, l = tid & 63, lo5 = l & 31, hi = l >> 5;
  const int tq0 = tblk * 256 + w * 64;

  bf16x8 q[2][4];
  {
    const unsigned short* Qb = QT + ((size_t)(b * 2048 + tq0 + lo5)) * 1024 + h * 64 + hi * 8;
    #pragma unroll
    for (int tb = 0; tb < 2; ++tb)
      #pragma unroll
      for (int kb = 0; kb < 4; ++kb)
        q[tb][kb] = *(const bf16x8*)(Qb + (size_t)tb * 32 * 1024 + kb * 16);
  }

  f32x16 o[2][2] = {};
  float lr[2] = {0.f, 0.f};

  const int srow0 = tid >> 3, sslot = tid & 7;
  const int ch0 = sslot ^ (srow0 & 7);
  const int ch1 = sslot ^ ((32 + srow0) & 7);
  const unsigned short* kp0 = KT + ((size_t)(b * 2048 + srow0)) * 1024 + h * 64 + ch0 * 8;
  const unsigned short* kp1 = KT + ((size_t)(b * 2048 + 32 + srow0)) * 1024 + h * 64 + ch1 * 8;
  const unsigned short* vp0 = V + ((size_t)(b * 1024 + h * 64 + srow0)) * 2048 + ch0 * 8;
  const unsigned short* vp1 = V + ((size_t)(b * 1024 + h * 64 + 32 + srow0)) * 2048 + ch1 * 8;

  auto stage = [&](char* buf) {
    GLOAD_LDS16(kp0, buf + tid * 16);
    GLOAD_LDS16(kp1, buf + 4096 + tid * 16);
    GLOAD_LDS16(vp0, buf + 8192 + tid * 16);
    GLOAD_LDS16(vp1, buf + 12288 + tid * 16);
    kp0 += 64 * 1024; kp1 += 64 * 1024;
    vp0 += 64; vp1 += 64;
  };

  stage(kv[0]);
  stage(kv[1]);

  char* bufc = kv[0];
  char* bufs = kv[2];

  for (int t = 0; t < 32; ++t) {
    if (t == 31) asm volatile("s_waitcnt vmcnt(0)" ::: "memory");
    else         asm volatile("s_waitcnt vmcnt(4)" ::: "memory");
    __builtin_amdgcn_s_barrier();
    asm volatile("" ::: "memory");
    if (t < 30) stage(bufs);

    const char* Ks = bufc;
    const char* Vs = bufc + 8192;

    bf16x8 ka[2][4];
    #pragma unroll
    for (int sblk = 0; sblk < 2; ++sblk)
      #pragma unroll
      for (int kb = 0; kb < 4; ++kb) {
        int row = sblk * 32 + lo5;
        ka[sblk][kb] = *(const bf16x8*)(Ks + row * 128 + SWZ(row, kb * 32 + hi * 16));
      }

    u32x4 pa[2][4];
    #pragma unroll
    for (int tb = 0; tb < 2; ++tb) {
      f32x16 p0 = {}, p1 = {};
      #pragma unroll
      for (int kb = 0; kb < 4; ++kb) {
        p0 = __builtin_amdgcn_mfma_f32_32x32x16_bf16(ka[0][kb], q[tb][kb], p0, 0, 0, 0);
        p1 = __builtin_amdgcn_mfma_f32_32x32x16_bf16(ka[1][kb], q[tb][kb], p1, 0, 0, 0);
      }

      float ls0 = 0.f, ls1 = 0.f, ls2 = 0.f, ls3 = 0.f;
      #pragma unroll
      for (int r = 0; r < 16; r += 4) {
        float e0 = fexp2(p0[r]), e1 = fexp2(p0[r + 1]), e2 = fexp2(p0[r + 2]), e3 = fexp2(p0[r + 3]);
        p0[r] = e0; p0[r + 1] = e1; p0[r + 2] = e2; p0[r + 3] = e3;
        ls0 += e0; ls1 += e1; ls2 += e2; ls3 += e3;
      }
      #pragma unroll
      for (int r = 0; r < 16; r += 4) {
        float e0 = fexp2(p1[r]), e1 = fexp2(p1[r + 1]), e2 = fexp2(p1[r + 2]), e3 = fexp2(p1[r + 3]);
        p1[r] = e0; p1[r + 1] = e1; p1[r + 2] = e2; p1[r + 3] = e3;
        ls0 += e0; ls1 += e1; ls2 += e2; ls3 += e3;
      }
      lr[tb] += (ls0 + ls1) + (ls2 + ls3);

      u32x2 ra = plswap(cvtpk(p0[0], p0[1]), cvtpk(p0[4], p0[5]));
      u32x2 rb = plswap(cvtpk(p0[2], p0[3]), cvtpk(p0[6], p0[7]));
      pa[tb][0] = (u32x4){ra[0], rb[0], ra[1], rb[1]};
      u32x2 rc = plswap(cvtpk(p0[8], p0[9]), cvtpk(p0[12], p0[13]));
      u32x2 rd = plswap(cvtpk(p0[10], p0[11]), cvtpk(p0[14], p0[15]));
      pa[tb][1] = (u32x4){rc[0], rd[0], rc[1], rd[1]};
      u32x2 re = plswap(cvtpk(p1[0], p1[1]), cvtpk(p1[4], p1[5]));
      u32x2 rf = plswap(cvtpk(p1[2], p1[3]), cvtpk(p1[6], p1[7]));
      pa[tb][2] = (u32x4){re[0], rf[0], re[1], rf[1]};
      u32x2 rg = plswap(cvtpk(p1[8], p1[9]), cvtpk(p1[12], p1[13]));
      u32x2 rh = plswap(cvtpk(p1[10], p1[11]), cvtpk(p1[14], p1[15]));
      pa[tb][3] = (u32x4){rg[0], rh[0], rg[1], rh[1]};
    }

    #pragma unroll
    for (int sb = 0; sb < 4; ++sb)
      #pragma unroll
      for (int kb2 = 0; kb2 < 2; ++kb2) {
        int row = kb2 * 32 + lo5;
        bf16x8 vb = *(const bf16x8*)(Vs + row * 128 + SWZ(row, sb * 32 + hi * 16));
        o[0][kb2] = __builtin_amdgcn_mfma_f32_32x32x16_bf16(
            __builtin_bit_cast(bf16x8, pa[0][sb]), vb, o[0][kb2], 0, 0, 0);
        o[1][kb2] = __builtin_amdgcn_mfma_f32_32x32x16_bf16(
            __builtin_bit_cast(bf16x8, pa[1][sb]), vb, o[1][kb2], 0, 0, 0);
      }

    bufc += 16384; if (bufc == kv[0] + 49152) bufc = kv[0];
    bufs += 16384; if (bufs == kv[0] + 49152) bufs = kv[0];
  }

  #pragma unroll
  for (int tb = 0; tb < 2; ++tb) {
    float lt = lr[tb] + __shfl_xor(lr[tb], 32);
    if (hi == 0) lbuf[w][lo5] = 1.0f / lt;
    unsigned short* Ob = OT + ((size_t)(b * 2048 + tq0 + tb * 32)) * 1024 + h * 64 + lo5;
    #pragma unroll
    for (int r = 0; r < 16; ++r) {
      int srow = (r & 3) + 8 * (r >> 2) + 4 * hi;
      float inv = lbuf[w][srow];
      Ob[(size_t)srow * 1024 + 0]  = f2bf(o[tb][0][r] * inv);
      Ob[(size_t)srow * 1024 + 32] = f2bf(o[tb][1][r] * inv);
    }
  }
}

// ---------------- launch ----------------
extern "C" void kernel_launch(void* const* d_in, const int* in_sizes, int n_in,
                              void* d_out, int out_size, void* d_ws, size_t ws_size,
                              hipStream_t stream) {
  const float* x  = (const float*)d_in[0];
  const float* c  = (const float*)d_in[1];
  const float* Wq = (const float*)d_in[2];
  const float* bq = (const float*)d_in[3];
  const float* Wk = (const float*)d_in[4];
  const float* bk = (const float*)d_in[5];
  const float* Wv = (const float*)d_in[6];
  const float* bv = (const float*)d_in[7];
  const float* Wo = (const float*)d_in[8];
  const float* bo = (const float*)d_in[9];

  const size_t MB = 1024 * 1024;
  char* ws = (char*)d_ws;
  unsigned short* wqb = (unsigned short*)(ws + 0 * MB);
  unsigned short* wkb = (unsigned short*)(ws + 2 * MB);
  unsigned short* wvb = (unsigned short*)(ws + 4 * MB);
  unsigned short* wob = (unsigned short*)(ws + 6 * MB);
  unsigned short* xT  = (unsigned short*)(ws + 8 * MB);   // [B][T][C] bf16, 16MB
  unsigned short* cT  = (unsigned short*)(ws + 24 * MB);
  unsigned short* QT  = (unsigned short*)(ws + 40 * MB);
  unsigned short* KT  = (unsigned short*)(ws + 56 * MB);
  unsigned short* Vb  = (unsigned short*)(ws + 72 * MB);  // [B][C][T] bf16
  unsigned short* OT  = xT;  // reuse: x dead after QKV gemm

  prep_inputs<<<dim3(64, 32, 12), 256, 0, stream>>>(x, c, Wq, Wk, Wv, Wo,
                                                    xT, cT, wqb, wkb, wvb, wob);

  qkv_gemm3<<<dim3(1536), 256, 0, stream>>>(xT, cT, wqb, wkb, wvb, bq, bk, bv, QT, KT, Vb);

  attn_kernel8<<<dim3(512), 256, 0, stream>>>(QT, KT, Vb, OT);

  gemm_out3<<<dim3(512), 256, 0, stream>>>(wob, OT, (float*)d_out, bo);
}